// Round 6
// baseline (247.740 us; speedup 1.0000x reference)
//
#include <hip/hip_runtime.h>
#include <hip/hip_bf16.h>

typedef __bf16 bf16_t;
typedef __bf16 bf16x4 __attribute__((ext_vector_type(4)));
typedef __bf16 bf16x8 __attribute__((ext_vector_type(8)));
typedef float floatx4 __attribute__((ext_vector_type(4)));

#define SEQ    8192
#define DM     1024
#define NHEADS 16
#define HDIM   64

// async global->LDS, 16B per lane; LDS dest is wave-uniform base + lane*16
__device__ __forceinline__ void async_ld16(bf16_t* lds, const bf16_t* g) {
  __builtin_amdgcn_global_load_lds(
      (__attribute__((address_space(1))) void*)g,
      (__attribute__((address_space(3))) void*)lds, 16, 0, 0);
}

// one launch converts x (8192 blocks) + 4 weight matrices (1024 blocks each)
__global__ __launch_bounds__(256)
void cvt_all(const float* __restrict__ x,  const float* __restrict__ qw,
             const float* __restrict__ kw, const float* __restrict__ vw,
             const float* __restrict__ ow,
             bf16_t* __restrict__ Xb,  bf16_t* __restrict__ QWb,
             bf16_t* __restrict__ KWb, bf16_t* __restrict__ VWb,
             bf16_t* __restrict__ OWb) {
  const int b = blockIdx.x;
  const float* in; bf16_t* out; int g;
  if (b < 8192) { in = x; out = Xb; g = b; }
  else {
    const int w  = (b - 8192) >> 10;
    const int wb = (b - 8192) & 1023;
    switch (w) {
      case 0:  in = qw; out = QWb; break;
      case 1:  in = kw; out = KWb; break;
      case 2:  in = vw; out = VWb; break;
      default: in = ow; out = OWb; break;
    }
    g = wb;
  }
  const int idx = (g * 256 + threadIdx.x) * 4;
  float4 v = *(const float4*)(in + idx);
  bf16x4 o = { (bf16_t)v.x, (bf16_t)v.y, (bf16_t)v.z, (bf16_t)v.w };
  *(bf16x4*)(out + idx) = o;
}

// ---------- QKV projection: 128x128 tile, z selects matrix (773 TF measured) ----------
__global__ __launch_bounds__(256)
void gemm_qkv(const bf16_t* __restrict__ A,
              const bf16_t* __restrict__ Bq, const bf16_t* __restrict__ Bk,
              const bf16_t* __restrict__ Bv,
              bf16_t* __restrict__ Cq, bf16_t* __restrict__ Ck, bf16_t* __restrict__ Cv)
{
  const bf16_t* B = (blockIdx.z == 0) ? Bq : (blockIdx.z == 1) ? Bk : Bv;
  bf16_t*       C = (blockIdx.z == 0) ? Cq : (blockIdx.z == 1) ? Ck : Cv;
  constexpr int Kdim = DM;
  __shared__ __attribute__((aligned(16))) bf16_t sA[128 * 32];
  __shared__ __attribute__((aligned(16))) bf16_t sB[128 * 32];

  const int tid  = threadIdx.x;
  const int wave = tid >> 6;
  const int lane = tid & 63;
  const int quad = lane >> 4;
  const int r16  = lane & 15;
  const int wr   = (wave >> 1) * 64;
  const int wc   = (wave & 1) * 64;

  const size_t arow0 = (size_t)blockIdx.x * 128 + wave * 32 + (lane >> 2);
  const size_t brow0 = (size_t)blockIdx.y * 128 + wave * 32 + (lane >> 2);
  const bf16_t* Ag = A + arow0 * Kdim + (lane & 3) * 8;
  const bf16_t* Bg = B + brow0 * Kdim + (lane & 3) * 8;
  bf16_t* sAw = sA + wave * 32 * 32;
  bf16_t* sBw = sB + wave * 32 * 32;

  floatx4 acc[4][4];
  #pragma unroll
  for (int i = 0; i < 4; ++i)
    #pragma unroll
    for (int j = 0; j < 4; ++j)
      acc[i][j] = (floatx4)(0.0f);

  for (int ko = 0; ko < Kdim; ko += 32) {
    async_ld16(sAw,           Ag + ko);
    async_ld16(sAw + 16 * 32, Ag + 16 * Kdim + ko);
    async_ld16(sBw,           Bg + ko);
    async_ld16(sBw + 16 * 32, Bg + 16 * Kdim + ko);
    __syncthreads();

    bf16x8 af[4], bfr[4];
    #pragma unroll
    for (int mi = 0; mi < 4; ++mi)
      af[mi] = *(const bf16x8*)&sA[(wr + mi * 16 + r16) * 32 + quad * 8];
    #pragma unroll
    for (int ni = 0; ni < 4; ++ni)
      bfr[ni] = *(const bf16x8*)&sB[(wc + ni * 16 + r16) * 32 + quad * 8];

    #pragma unroll
    for (int mi = 0; mi < 4; ++mi)
      #pragma unroll
      for (int ni = 0; ni < 4; ++ni)
        acc[mi][ni] = __builtin_amdgcn_mfma_f32_16x16x32_bf16(af[mi], bfr[ni], acc[mi][ni], 0, 0, 0);

    __syncthreads();
  }

  // C/D layout: col = lane&15, row = (lane>>4)*4 + reg  [measured m89/m91]
  const int crow0 = blockIdx.x * 128 + wr + quad * 4;
  const int ccol0 = blockIdx.y * 128 + wc + r16;
  #pragma unroll
  for (int mi = 0; mi < 4; ++mi)
    #pragma unroll
    for (int ni = 0; ni < 4; ++ni)
      #pragma unroll
      for (int r = 0; r < 4; ++r)
        C[(size_t)(crow0 + mi * 16 + r) * DM + (ccol0 + ni * 16)] = (bf16_t)acc[mi][ni][r];
}

// ---------- Output projection: 128x64 tile -> 1024 blocks (4/CU vs old 2/CU) ----------
__global__ __launch_bounds__(256)
void gemm_out(const bf16_t* __restrict__ A, const bf16_t* __restrict__ B,
              float* __restrict__ C)
{
  constexpr int Kdim = DM;
  __shared__ __attribute__((aligned(16))) bf16_t sA[128 * 32];
  __shared__ __attribute__((aligned(16))) bf16_t sB[64 * 32];

  const int tid  = threadIdx.x;
  const int wave = tid >> 6;
  const int lane = tid & 63;
  const int quad = lane >> 4;
  const int r16  = lane & 15;
  const int wr   = (wave >> 1) * 64;   // wave row offset in 128-row tile
  const int wc   = (wave & 1) * 32;    // wave col offset in 64-col tile

  const size_t arow = (size_t)blockIdx.x * 128 + wave * 32 + (lane >> 2);
  const size_t brow = (size_t)blockIdx.y * 64 + wave * 16 + (lane >> 2);
  const bf16_t* Ag = A + arow * Kdim + (lane & 3) * 8;
  const bf16_t* Bg = B + brow * Kdim + (lane & 3) * 8;
  bf16_t* sAw = sA + wave * 32 * 32;
  bf16_t* sBw = sB + wave * 16 * 32;

  floatx4 acc[4][2];
  #pragma unroll
  for (int i = 0; i < 4; ++i)
    #pragma unroll
    for (int j = 0; j < 2; ++j)
      acc[i][j] = (floatx4)(0.0f);

  for (int ko = 0; ko < Kdim; ko += 32) {
    async_ld16(sAw,           Ag + ko);
    async_ld16(sAw + 16 * 32, Ag + 16 * Kdim + ko);
    async_ld16(sBw,           Bg + ko);
    __syncthreads();

    bf16x8 af[4], bfr[2];
    #pragma unroll
    for (int mi = 0; mi < 4; ++mi)
      af[mi] = *(const bf16x8*)&sA[(wr + mi * 16 + r16) * 32 + quad * 8];
    #pragma unroll
    for (int ni = 0; ni < 2; ++ni)
      bfr[ni] = *(const bf16x8*)&sB[(wc + ni * 16 + r16) * 32 + quad * 8];

    #pragma unroll
    for (int mi = 0; mi < 4; ++mi)
      #pragma unroll
      for (int ni = 0; ni < 2; ++ni)
        acc[mi][ni] = __builtin_amdgcn_mfma_f32_16x16x32_bf16(af[mi], bfr[ni], acc[mi][ni], 0, 0, 0);

    __syncthreads();
  }

  const int crow0 = blockIdx.x * 128 + wr + quad * 4;
  const int ccol0 = blockIdx.y * 64 + wc + r16;
  #pragma unroll
  for (int mi = 0; mi < 4; ++mi)
    #pragma unroll
    for (int ni = 0; ni < 2; ++ni)
      #pragma unroll
      for (int r = 0; r < 4; ++r)
        C[(size_t)(crow0 + mi * 16 + r) * DM + (ccol0 + ni * 16)] = acc[mi][ni][r];
}

// ---------- Attention: one wave per query i, all 16 heads; fixed 14-iter unroll ----------
// Lane L owns dims [16L,16L+16) (head = L>>2). Attended set {i} U {i-2^t}.
// Padded to a compile-time trip count: invalid positions clamp to row 0 and get
// score=-inf (weight exactly 0), so ALL load addresses are loop-independent and
// the compiler can hoist/pipeline the K/V loads past the serial softmax chain.
__global__ __launch_bounds__(256)
void dilated_attn(const bf16_t* __restrict__ Q, const bf16_t* __restrict__ K,
                  const bf16_t* __restrict__ V, bf16_t* O)
{
  const int lane = threadIdx.x & 63;
  const int qb   = (blockIdx.x & 7) * 256 + (blockIdx.x >> 3);  // XCD-affinity swizzle
  const int i    = qb * 4 + (threadIdx.x >> 6);
  const size_t base = (size_t)i * DM + lane * 16;

  bf16x8 q0 = *(const bf16x8*)(Q + base);
  bf16x8 q1 = *(const bf16x8*)(Q + base + 8);
  float qf[16];
  #pragma unroll
  for (int j = 0; j < 8; ++j) { qf[j] = (float)q0[j] * 0.125f; qf[j + 8] = (float)q1[j] * 0.125f; }

  float m = -INFINITY, l = 0.0f;
  float acc[16];
  #pragma unroll
  for (int j = 0; j < 16; ++j) acc[j] = 0.0f;

  #pragma unroll
  for (int t = 0; t < 14; ++t) {
    const int offv  = (t == 0) ? 0 : (1 << (t - 1));
    const int pn    = i - offv;
    const bool valid = (pn >= 0);          // wave-uniform
    const size_t nb = (size_t)(valid ? pn : 0) * DM + lane * 16;
    bf16x8 k0 = *(const bf16x8*)(K + nb), k1 = *(const bf16x8*)(K + nb + 8);
    bf16x8 v0 = *(const bf16x8*)(V + nb), v1 = *(const bf16x8*)(V + nb + 8);

    float sc = 0.0f;
    #pragma unroll
    for (int j = 0; j < 8; ++j) sc += qf[j] * (float)k0[j] + qf[j + 8] * (float)k1[j];
    sc += __shfl_xor(sc, 1, 64);           // sum across the 4 lanes of this head
    sc += __shfl_xor(sc, 2, 64);
    sc = valid ? sc : -INFINITY;           // padded position -> weight 0

    float mn = fmaxf(m, sc);
    float co = __expf(m - mn);
    float w  = __expf(sc - mn);
    l = l * co + w;
    m = mn;
    #pragma unroll
    for (int j = 0; j < 8; ++j) {
      acc[j]     = acc[j]     * co + w * (float)v0[j];
      acc[j + 8] = acc[j + 8] * co + w * (float)v1[j];
    }
  }

  const float inv = 1.0f / l;
  bf16x8 o0, o1;
  #pragma unroll
  for (int j = 0; j < 8; ++j) { o0[j] = (bf16_t)(acc[j] * inv); o1[j] = (bf16_t)(acc[j + 8] * inv); }
  *(bf16x8*)(O + base)     = o0;
  *(bf16x8*)(O + base + 8) = o1;
}

extern "C" void kernel_launch(void* const* d_in, const int* in_sizes, int n_in,
                              void* d_out, int out_size, void* d_ws, size_t ws_size,
                              hipStream_t stream) {
  (void)in_sizes; (void)n_in; (void)out_size; (void)ws_size;
  const float* x  = (const float*)d_in[0];
  const float* qw = (const float*)d_in[1];
  const float* kw = (const float*)d_in[2];
  const float* vw = (const float*)d_in[3];
  const float* ow = (const float*)d_in[4];
  // d_in[5] (positions) and d_in[6] (attend_mask) recomputed analytically in-kernel
  float* out = (float*)d_out;

  bf16_t* Xb  = (bf16_t*)d_ws;                       // 8192x1024
  bf16_t* Qb  = Xb  + (size_t)SEQ * DM;
  bf16_t* Kb  = Qb  + (size_t)SEQ * DM;
  bf16_t* Vb  = Kb  + (size_t)SEQ * DM;
  bf16_t* QWb = Vb  + (size_t)SEQ * DM;              // 1024x1024 x4
  bf16_t* KWb = QWb + (size_t)DM * DM;
  bf16_t* VWb = KWb + (size_t)DM * DM;
  bf16_t* OWb = VWb + (size_t)DM * DM;
  bf16_t* AO  = Qb;  // alias Q: each attn wave reads its own q row before writing it

  cvt_all<<<dim3(8192 + 4096), dim3(256), 0, stream>>>(x, qw, kw, vw, ow,
                                                       Xb, QWb, KWb, VWb, OWb);

  dim3 block(256);
  gemm_qkv<<<dim3(SEQ / 128, DM / 128, 3), block, 0, stream>>>(Xb, QWb, KWb, VWb, Qb, Kb, Vb);
  dilated_attn<<<dim3(SEQ / 4), block, 0, stream>>>(Qb, Kb, Vb, AO);
  gemm_out<<<dim3(SEQ / 128, DM / 64), block, 0, stream>>>(AO, OWb, out);
}

// Round 7
// 240.823 us; speedup vs baseline: 1.0287x; 1.0287x over previous
//
#include <hip/hip_runtime.h>
#include <hip/hip_bf16.h>

typedef __bf16 bf16_t;
typedef __bf16 bf16x4 __attribute__((ext_vector_type(4)));
typedef __bf16 bf16x8 __attribute__((ext_vector_type(8)));
typedef float floatx4 __attribute__((ext_vector_type(4)));

#define SEQ    8192
#define DM     1024
#define NHEADS 16
#define HDIM   64

// async global->LDS, 16B per lane; LDS dest is wave-uniform base + lane*16
__device__ __forceinline__ void async_ld16(bf16_t* lds, const bf16_t* g) {
  __builtin_amdgcn_global_load_lds(
      (__attribute__((address_space(1))) void*)g,
      (__attribute__((address_space(3))) void*)lds, 16, 0, 0);
}

// one launch converts x (8192 blocks) + 4 weight matrices (1024 blocks each)
__global__ __launch_bounds__(256)
void cvt_all(const float* __restrict__ x,  const float* __restrict__ qw,
             const float* __restrict__ kw, const float* __restrict__ vw,
             const float* __restrict__ ow,
             bf16_t* __restrict__ Xb,  bf16_t* __restrict__ QWb,
             bf16_t* __restrict__ KWb, bf16_t* __restrict__ VWb,
             bf16_t* __restrict__ OWb) {
  const int b = blockIdx.x;
  const float* in; bf16_t* out; int g;
  if (b < 8192) { in = x; out = Xb; g = b; }
  else {
    const int w  = (b - 8192) >> 10;
    const int wb = (b - 8192) & 1023;
    switch (w) {
      case 0:  in = qw; out = QWb; break;
      case 1:  in = kw; out = KWb; break;
      case 2:  in = vw; out = VWb; break;
      default: in = ow; out = OWb; break;
    }
    g = wb;
  }
  const int idx = (g * 256 + threadIdx.x) * 4;
  float4 v = *(const float4*)(in + idx);
  bf16x4 o = { (bf16_t)v.x, (bf16_t)v.y, (bf16_t)v.z, (bf16_t)v.w };
  *(bf16x4*)(out + idx) = o;
}

// ---------- QKV projection: 128x128 tile, BK=64 (16 K-iters -> half the barrier drains) ----------
__global__ __launch_bounds__(256)
void gemm_qkv(const bf16_t* __restrict__ A,
              const bf16_t* __restrict__ Bq, const bf16_t* __restrict__ Bk,
              const bf16_t* __restrict__ Bv,
              bf16_t* __restrict__ Cq, bf16_t* __restrict__ Ck, bf16_t* __restrict__ Cv)
{
  const bf16_t* B = (blockIdx.z == 0) ? Bq : (blockIdx.z == 1) ? Bk : Bv;
  bf16_t*       C = (blockIdx.z == 0) ? Cq : (blockIdx.z == 1) ? Ck : Cv;
  constexpr int Kdim = DM;
  __shared__ __attribute__((aligned(16))) bf16_t sA[128 * 64];   // 16 KB
  __shared__ __attribute__((aligned(16))) bf16_t sB[128 * 64];   // 16 KB

  const int tid  = threadIdx.x;
  const int wave = tid >> 6;
  const int lane = tid & 63;
  const int quad = lane >> 4;
  const int r16  = lane & 15;
  const int wr   = (wave >> 1) * 64;
  const int wc   = (wave & 1) * 64;

  // staging, BK=64: lane L -> row L/8, k-chunk (L%8)*8; LDS offset L*16B (contiguous).
  // Each async_ld16 covers 8 rows; 4 instructions cover the wave's 32 rows.
  const size_t arow0 = (size_t)blockIdx.x * 128 + wave * 32 + (lane >> 3);
  const size_t brow0 = (size_t)blockIdx.y * 128 + wave * 32 + (lane >> 3);
  const bf16_t* Ag = A + arow0 * Kdim + (lane & 7) * 8;
  const bf16_t* Bg = B + brow0 * Kdim + (lane & 7) * 8;
  bf16_t* sAw = sA + wave * 32 * 64;
  bf16_t* sBw = sB + wave * 32 * 64;

  floatx4 acc[4][4];
  #pragma unroll
  for (int i = 0; i < 4; ++i)
    #pragma unroll
    for (int j = 0; j < 4; ++j)
      acc[i][j] = (floatx4)(0.0f);

  for (int ko = 0; ko < Kdim; ko += 64) {
    #pragma unroll
    for (int n = 0; n < 4; ++n) {
      async_ld16(sAw + n * 512, Ag + (size_t)n * 8 * Kdim + ko);
      async_ld16(sBw + n * 512, Bg + (size_t)n * 8 * Kdim + ko);
    }
    __syncthreads();   // drains vmcnt, then barrier

    #pragma unroll
    for (int s = 0; s < 2; ++s) {      // two K=32 sub-steps; registers reused
      bf16x8 af[4], bfr[4];
      #pragma unroll
      for (int mi = 0; mi < 4; ++mi)
        af[mi] = *(const bf16x8*)&sA[(wr + mi * 16 + r16) * 64 + s * 32 + quad * 8];
      #pragma unroll
      for (int ni = 0; ni < 4; ++ni)
        bfr[ni] = *(const bf16x8*)&sB[(wc + ni * 16 + r16) * 64 + s * 32 + quad * 8];

      #pragma unroll
      for (int mi = 0; mi < 4; ++mi)
        #pragma unroll
        for (int ni = 0; ni < 4; ++ni)
          acc[mi][ni] = __builtin_amdgcn_mfma_f32_16x16x32_bf16(af[mi], bfr[ni], acc[mi][ni], 0, 0, 0);
    }

    __syncthreads();   // protect LDS before next stage overwrites
  }

  // C/D layout: col = lane&15, row = (lane>>4)*4 + reg  [measured m89/m91]
  const int crow0 = blockIdx.x * 128 + wr + quad * 4;
  const int ccol0 = blockIdx.y * 128 + wc + r16;
  #pragma unroll
  for (int mi = 0; mi < 4; ++mi)
    #pragma unroll
    for (int ni = 0; ni < 4; ++ni)
      #pragma unroll
      for (int r = 0; r < 4; ++r)
        C[(size_t)(crow0 + mi * 16 + r) * DM + (ccol0 + ni * 16)] = (bf16_t)acc[mi][ni][r];
}

// ---------- Output projection: 128x64 tile -> 1024 blocks (4/CU) ----------
__global__ __launch_bounds__(256)
void gemm_out(const bf16_t* __restrict__ A, const bf16_t* __restrict__ B,
              float* __restrict__ C)
{
  constexpr int Kdim = DM;
  __shared__ __attribute__((aligned(16))) bf16_t sA[128 * 32];
  __shared__ __attribute__((aligned(16))) bf16_t sB[64 * 32];

  const int tid  = threadIdx.x;
  const int wave = tid >> 6;
  const int lane = tid & 63;
  const int quad = lane >> 4;
  const int r16  = lane & 15;
  const int wr   = (wave >> 1) * 64;   // wave row offset in 128-row tile
  const int wc   = (wave & 1) * 32;    // wave col offset in 64-col tile

  const size_t arow = (size_t)blockIdx.x * 128 + wave * 32 + (lane >> 2);
  const size_t brow = (size_t)blockIdx.y * 64 + wave * 16 + (lane >> 2);
  const bf16_t* Ag = A + arow * Kdim + (lane & 3) * 8;
  const bf16_t* Bg = B + brow * Kdim + (lane & 3) * 8;
  bf16_t* sAw = sA + wave * 32 * 32;
  bf16_t* sBw = sB + wave * 16 * 32;

  floatx4 acc[4][2];
  #pragma unroll
  for (int i = 0; i < 4; ++i)
    #pragma unroll
    for (int j = 0; j < 2; ++j)
      acc[i][j] = (floatx4)(0.0f);

  for (int ko = 0; ko < Kdim; ko += 32) {
    async_ld16(sAw,           Ag + ko);
    async_ld16(sAw + 16 * 32, Ag + 16 * Kdim + ko);
    async_ld16(sBw,           Bg + ko);
    __syncthreads();

    bf16x8 af[4], bfr[2];
    #pragma unroll
    for (int mi = 0; mi < 4; ++mi)
      af[mi] = *(const bf16x8*)&sA[(wr + mi * 16 + r16) * 32 + quad * 8];
    #pragma unroll
    for (int ni = 0; ni < 2; ++ni)
      bfr[ni] = *(const bf16x8*)&sB[(wc + ni * 16 + r16) * 32 + quad * 8];

    #pragma unroll
    for (int mi = 0; mi < 4; ++mi)
      #pragma unroll
      for (int ni = 0; ni < 2; ++ni)
        acc[mi][ni] = __builtin_amdgcn_mfma_f32_16x16x32_bf16(af[mi], bfr[ni], acc[mi][ni], 0, 0, 0);

    __syncthreads();
  }

  const int crow0 = blockIdx.x * 128 + wr + quad * 4;
  const int ccol0 = blockIdx.y * 64 + wc + r16;
  #pragma unroll
  for (int mi = 0; mi < 4; ++mi)
    #pragma unroll
    for (int ni = 0; ni < 2; ++ni)
      #pragma unroll
      for (int r = 0; r < 4; ++r)
        C[(size_t)(crow0 + mi * 16 + r) * DM + (ccol0 + ni * 16)] = acc[mi][ni][r];
}

// ---------- Attention: one wave per query i, all 16 heads (round-5 paced loop) ----------
// Lane L owns dims [16L,16L+16) (head = L>>2). Attended set {i} U {i-2^t}.
// Paced while-loop with depth-1 prefetch: high occupancy + warm-L2 pacing beats
// the full-unroll variant (round 6: VGPR 148, occ 10%, FETCH 2x -- regressed).
__global__ __launch_bounds__(256)
void dilated_attn(const bf16_t* __restrict__ Q, const bf16_t* __restrict__ K,
                  const bf16_t* __restrict__ V, bf16_t* O)
{
  const int lane = threadIdx.x & 63;
  const int qb   = (blockIdx.x & 7) * 256 + (blockIdx.x >> 3);  // XCD-affinity swizzle
  const int i    = qb * 4 + (threadIdx.x >> 6);
  const size_t base = (size_t)i * DM + lane * 16;

  bf16x8 q0 = *(const bf16x8*)(Q + base);
  bf16x8 q1 = *(const bf16x8*)(Q + base + 8);
  float qf[16];
  #pragma unroll
  for (int j = 0; j < 8; ++j) { qf[j] = (float)q0[j] * 0.125f; qf[j + 8] = (float)q1[j] * 0.125f; }

  float m = -INFINITY, l = 0.0f;
  float acc[16];
  #pragma unroll
  for (int j = 0; j < 16; ++j) acc[j] = 0.0f;

  int off = 1;
  bf16x8 k0 = *(const bf16x8*)(K + base), k1 = *(const bf16x8*)(K + base + 8);
  bf16x8 v0 = *(const bf16x8*)(V + base), v1 = *(const bf16x8*)(V + base + 8);

  while (true) {
    const int pn = i - off;
    const bool more = (pn >= 0);           // wave-uniform
    bf16x8 nk0, nk1, nv0, nv1;
    if (more) {                            // prefetch next position
      size_t nb = (size_t)pn * DM + lane * 16;
      nk0 = *(const bf16x8*)(K + nb); nk1 = *(const bf16x8*)(K + nb + 8);
      nv0 = *(const bf16x8*)(V + nb); nv1 = *(const bf16x8*)(V + nb + 8);
    }

    float sc = 0.0f;
    #pragma unroll
    for (int j = 0; j < 8; ++j) sc += qf[j] * (float)k0[j] + qf[j + 8] * (float)k1[j];
    sc += __shfl_xor(sc, 1, 64);           // sum across the 4 lanes of this head
    sc += __shfl_xor(sc, 2, 64);

    float mn = fmaxf(m, sc);
    float co = __expf(m - mn);
    float w  = __expf(sc - mn);
    l = l * co + w;
    m = mn;
    #pragma unroll
    for (int j = 0; j < 8; ++j) {
      acc[j]     = acc[j]     * co + w * (float)v0[j];
      acc[j + 8] = acc[j + 8] * co + w * (float)v1[j];
    }

    if (!more) break;
    k0 = nk0; k1 = nk1; v0 = nv0; v1 = nv1;
    off <<= 1;
  }

  const float inv = 1.0f / l;
  bf16x8 o0, o1;
  #pragma unroll
  for (int j = 0; j < 8; ++j) { o0[j] = (bf16_t)(acc[j] * inv); o1[j] = (bf16_t)(acc[j + 8] * inv); }
  *(bf16x8*)(O + base)     = o0;
  *(bf16x8*)(O + base + 8) = o1;
}

extern "C" void kernel_launch(void* const* d_in, const int* in_sizes, int n_in,
                              void* d_out, int out_size, void* d_ws, size_t ws_size,
                              hipStream_t stream) {
  (void)in_sizes; (void)n_in; (void)out_size; (void)ws_size;
  const float* x  = (const float*)d_in[0];
  const float* qw = (const float*)d_in[1];
  const float* kw = (const float*)d_in[2];
  const float* vw = (const float*)d_in[3];
  const float* ow = (const float*)d_in[4];
  // d_in[5] (positions) and d_in[6] (attend_mask) recomputed analytically in-kernel
  float* out = (float*)d_out;

  bf16_t* Xb  = (bf16_t*)d_ws;                       // 8192x1024
  bf16_t* Qb  = Xb  + (size_t)SEQ * DM;
  bf16_t* Kb  = Qb  + (size_t)SEQ * DM;
  bf16_t* Vb  = Kb  + (size_t)SEQ * DM;
  bf16_t* QWb = Vb  + (size_t)SEQ * DM;              // 1024x1024 x4
  bf16_t* KWb = QWb + (size_t)DM * DM;
  bf16_t* VWb = KWb + (size_t)DM * DM;
  bf16_t* OWb = VWb + (size_t)DM * DM;
  bf16_t* AO  = Qb;  // alias Q: each attn wave reads its own q row before writing it

  cvt_all<<<dim3(8192 + 4096), dim3(256), 0, stream>>>(x, qw, kw, vw, ow,
                                                       Xb, QWb, KWb, VWb, OWb);

  dim3 block(256);
  gemm_qkv<<<dim3(SEQ / 128, DM / 128, 3), block, 0, stream>>>(Xb, QWb, KWb, VWb, Qb, Kb, Vb);
  dilated_attn<<<dim3(SEQ / 4), block, 0, stream>>>(Qb, Kb, Vb, AO);
  gemm_out<<<dim3(SEQ / 128, DM / 64), block, 0, stream>>>(AO, OWb, out);
}

// Round 8
// 224.253 us; speedup vs baseline: 1.1047x; 1.0739x over previous
//
#include <hip/hip_runtime.h>
#include <hip/hip_bf16.h>

typedef __bf16 bf16_t;
typedef __bf16 bf16x4 __attribute__((ext_vector_type(4)));
typedef __bf16 bf16x8 __attribute__((ext_vector_type(8)));
typedef float floatx4 __attribute__((ext_vector_type(4)));

#define SEQ    8192
#define DM     1024
#define NHEADS 16
#define HDIM   64

// async global->LDS, 16B per lane; LDS dest is wave-uniform base + lane*16
__device__ __forceinline__ void async_ld16(bf16_t* lds, const bf16_t* g) {
  __builtin_amdgcn_global_load_lds(
      (__attribute__((address_space(1))) void*)g,
      (__attribute__((address_space(3))) void*)lds, 16, 0, 0);
}

// one launch converts x (8192 blocks) + 4 weight matrices (1024 blocks each)
__global__ __launch_bounds__(256)
void cvt_all(const float* __restrict__ x,  const float* __restrict__ qw,
             const float* __restrict__ kw, const float* __restrict__ vw,
             const float* __restrict__ ow,
             bf16_t* __restrict__ Xb,  bf16_t* __restrict__ QWb,
             bf16_t* __restrict__ KWb, bf16_t* __restrict__ VWb,
             bf16_t* __restrict__ OWb) {
  const int b = blockIdx.x;
  const float* in; bf16_t* out; int g;
  if (b < 8192) { in = x; out = Xb; g = b; }
  else {
    const int w  = (b - 8192) >> 10;
    const int wb = (b - 8192) & 1023;
    switch (w) {
      case 0:  in = qw; out = QWb; break;
      case 1:  in = kw; out = KWb; break;
      case 2:  in = vw; out = VWb; break;
      default: in = ow; out = OWb; break;
    }
    g = wb;
  }
  const int idx = (g * 256 + threadIdx.x) * 4;
  float4 v = *(const float4*)(in + idx);
  bf16x4 o = { (bf16_t)v.x, (bf16_t)v.y, (bf16_t)v.z, (bf16_t)v.w };
  *(bf16x4*)(out + idx) = o;
}

// XOR chunk swizzle: LDS slot c of row r holds global k-chunk c ^ ((r>>1)&3).
// Staging lane L (row L/4, slot L%4) therefore FETCHES global chunk
// (L%4) ^ ((L>>3)&3) -- a permutation within the same 64B row segment, so
// global coalescing is unchanged and the LDS dest stays lane*16B contiguous.
// Read: chunk q of row r is at slot q ^ ((r>>1)&3). Banks: rows 0..7 hit 8
// distinct 4-bank groups (all 32 banks), rows 8..15 repeat -> 2-way = free.

// ---------- QKV projection: 128x128 tile, BK=32, swizzled LDS ----------
__global__ __launch_bounds__(256)
void gemm_qkv(const bf16_t* __restrict__ A,
              const bf16_t* __restrict__ Bq, const bf16_t* __restrict__ Bk,
              const bf16_t* __restrict__ Bv,
              bf16_t* __restrict__ Cq, bf16_t* __restrict__ Ck, bf16_t* __restrict__ Cv)
{
  const bf16_t* B = (blockIdx.z == 0) ? Bq : (blockIdx.z == 1) ? Bk : Bv;
  bf16_t*       C = (blockIdx.z == 0) ? Cq : (blockIdx.z == 1) ? Ck : Cv;
  constexpr int Kdim = DM;
  __shared__ __attribute__((aligned(16))) bf16_t sA[128 * 32];
  __shared__ __attribute__((aligned(16))) bf16_t sB[128 * 32];

  const int tid  = threadIdx.x;
  const int wave = tid >> 6;
  const int lane = tid & 63;
  const int quad = lane >> 4;
  const int r16  = lane & 15;
  const int wr   = (wave >> 1) * 64;
  const int wc   = (wave & 1) * 64;

  // staging with swizzled fetch chunk
  const int gc = (lane & 3) ^ ((lane >> 3) & 3);
  const size_t arow0 = (size_t)blockIdx.x * 128 + wave * 32 + (lane >> 2);
  const size_t brow0 = (size_t)blockIdx.y * 128 + wave * 32 + (lane >> 2);
  const bf16_t* Ag = A + arow0 * Kdim + gc * 8;
  const bf16_t* Bg = B + brow0 * Kdim + gc * 8;
  bf16_t* sAw = sA + wave * 32 * 32;
  bf16_t* sBw = sB + wave * 32 * 32;

  // read-side swizzled slot offset (elements)
  const int slotA = ((quad ^ ((r16 >> 1) & 3)) * 8);

  floatx4 acc[4][4];
  #pragma unroll
  for (int i = 0; i < 4; ++i)
    #pragma unroll
    for (int j = 0; j < 4; ++j)
      acc[i][j] = (floatx4)(0.0f);

  for (int ko = 0; ko < Kdim; ko += 32) {
    async_ld16(sAw,           Ag + ko);
    async_ld16(sAw + 16 * 32, Ag + 16 * Kdim + ko);
    async_ld16(sBw,           Bg + ko);
    async_ld16(sBw + 16 * 32, Bg + 16 * Kdim + ko);
    __syncthreads();   // drains vmcnt, then barrier

    bf16x8 af[4], bfr[4];
    #pragma unroll
    for (int mi = 0; mi < 4; ++mi)
      af[mi] = *(const bf16x8*)&sA[(wr + mi * 16 + r16) * 32 + slotA];
    #pragma unroll
    for (int ni = 0; ni < 4; ++ni)
      bfr[ni] = *(const bf16x8*)&sB[(wc + ni * 16 + r16) * 32 + slotA];

    #pragma unroll
    for (int mi = 0; mi < 4; ++mi)
      #pragma unroll
      for (int ni = 0; ni < 4; ++ni)
        acc[mi][ni] = __builtin_amdgcn_mfma_f32_16x16x32_bf16(af[mi], bfr[ni], acc[mi][ni], 0, 0, 0);

    __syncthreads();   // protect LDS before next stage overwrites
  }

  // C/D layout: col = lane&15, row = (lane>>4)*4 + reg  [measured m89/m91]
  // fold softmax scale 1/sqrt(64) into Q here (saves VALU in attention)
  const float scl = (blockIdx.z == 0) ? 0.125f : 1.0f;
  const int crow0 = blockIdx.x * 128 + wr + quad * 4;
  const int ccol0 = blockIdx.y * 128 + wc + r16;
  #pragma unroll
  for (int mi = 0; mi < 4; ++mi)
    #pragma unroll
    for (int ni = 0; ni < 4; ++ni)
      #pragma unroll
      for (int r = 0; r < 4; ++r)
        C[(size_t)(crow0 + mi * 16 + r) * DM + (ccol0 + ni * 16)] = (bf16_t)(acc[mi][ni][r] * scl);
}

// ---------- Output projection: 128x64 tile (1024 blocks), swizzled LDS ----------
__global__ __launch_bounds__(256)
void gemm_out(const bf16_t* __restrict__ A, const bf16_t* __restrict__ B,
              float* __restrict__ C)
{
  constexpr int Kdim = DM;
  __shared__ __attribute__((aligned(16))) bf16_t sA[128 * 32];
  __shared__ __attribute__((aligned(16))) bf16_t sB[64 * 32];

  const int tid  = threadIdx.x;
  const int wave = tid >> 6;
  const int lane = tid & 63;
  const int quad = lane >> 4;
  const int r16  = lane & 15;
  const int wr   = (wave >> 1) * 64;   // wave row offset in 128-row tile
  const int wc   = (wave & 1) * 32;    // wave col offset in 64-col tile

  const int gc = (lane & 3) ^ ((lane >> 3) & 3);
  const size_t arow = (size_t)blockIdx.x * 128 + wave * 32 + (lane >> 2);
  const size_t brow = (size_t)blockIdx.y * 64 + wave * 16 + (lane >> 2);
  const bf16_t* Ag = A + arow * Kdim + gc * 8;
  const bf16_t* Bg = B + brow * Kdim + gc * 8;
  bf16_t* sAw = sA + wave * 32 * 32;
  bf16_t* sBw = sB + wave * 16 * 32;

  const int slotA = ((quad ^ ((r16 >> 1) & 3)) * 8);

  floatx4 acc[4][2];
  #pragma unroll
  for (int i = 0; i < 4; ++i)
    #pragma unroll
    for (int j = 0; j < 2; ++j)
      acc[i][j] = (floatx4)(0.0f);

  for (int ko = 0; ko < Kdim; ko += 32) {
    async_ld16(sAw,           Ag + ko);
    async_ld16(sAw + 16 * 32, Ag + 16 * Kdim + ko);
    async_ld16(sBw,           Bg + ko);
    __syncthreads();

    bf16x8 af[4], bfr[2];
    #pragma unroll
    for (int mi = 0; mi < 4; ++mi)
      af[mi] = *(const bf16x8*)&sA[(wr + mi * 16 + r16) * 32 + slotA];
    #pragma unroll
    for (int ni = 0; ni < 2; ++ni)
      bfr[ni] = *(const bf16x8*)&sB[(wc + ni * 16 + r16) * 32 + slotA];

    #pragma unroll
    for (int mi = 0; mi < 4; ++mi)
      #pragma unroll
      for (int ni = 0; ni < 2; ++ni)
        acc[mi][ni] = __builtin_amdgcn_mfma_f32_16x16x32_bf16(af[mi], bfr[ni], acc[mi][ni], 0, 0, 0);

    __syncthreads();
  }

  const int crow0 = blockIdx.x * 128 + wr + quad * 4;
  const int ccol0 = blockIdx.y * 64 + wc + r16;
  #pragma unroll
  for (int mi = 0; mi < 4; ++mi)
    #pragma unroll
    for (int ni = 0; ni < 2; ++ni)
      #pragma unroll
      for (int r = 0; r < 4; ++r)
        C[(size_t)(crow0 + mi * 16 + r) * DM + (ccol0 + ni * 16)] = acc[mi][ni][r];
}

// ---------- Attention: one wave per query i, all 16 heads (round-5 paced loop) ----------
// Lane L owns dims [16L,16L+16) (head = L>>2). Attended set {i} U {i-2^t}.
// Q arrives pre-scaled by 1/sqrt(64) (folded into gemm_qkv epilogue).
__global__ __launch_bounds__(256)
void dilated_attn(const bf16_t* __restrict__ Q, const bf16_t* __restrict__ K,
                  const bf16_t* __restrict__ V, bf16_t* O)
{
  const int lane = threadIdx.x & 63;
  const int qb   = (blockIdx.x & 7) * 256 + (blockIdx.x >> 3);  // XCD-affinity swizzle
  const int i    = qb * 4 + (threadIdx.x >> 6);
  const size_t base = (size_t)i * DM + lane * 16;

  bf16x8 q0 = *(const bf16x8*)(Q + base);
  bf16x8 q1 = *(const bf16x8*)(Q + base + 8);
  float qf[16];
  #pragma unroll
  for (int j = 0; j < 8; ++j) { qf[j] = (float)q0[j]; qf[j + 8] = (float)q1[j]; }

  float m = -INFINITY, l = 0.0f;
  float acc[16];
  #pragma unroll
  for (int j = 0; j < 16; ++j) acc[j] = 0.0f;

  int off = 1;
  bf16x8 k0 = *(const bf16x8*)(K + base), k1 = *(const bf16x8*)(K + base + 8);
  bf16x8 v0 = *(const bf16x8*)(V + base), v1 = *(const bf16x8*)(V + base + 8);

  while (true) {
    const int pn = i - off;
    const bool more = (pn >= 0);           // wave-uniform
    bf16x8 nk0, nk1, nv0, nv1;
    if (more) {                            // prefetch next position
      size_t nb = (size_t)pn * DM + lane * 16;
      nk0 = *(const bf16x8*)(K + nb); nk1 = *(const bf16x8*)(K + nb + 8);
      nv0 = *(const bf16x8*)(V + nb); nv1 = *(const bf16x8*)(V + nb + 8);
    }

    float sc = 0.0f;
    #pragma unroll
    for (int j = 0; j < 8; ++j) sc += qf[j] * (float)k0[j] + qf[j + 8] * (float)k1[j];
    sc += __shfl_xor(sc, 1, 64);           // sum across the 4 lanes of this head
    sc += __shfl_xor(sc, 2, 64);

    float mn = fmaxf(m, sc);
    float co = __expf(m - mn);
    float w  = __expf(sc - mn);
    l = l * co + w;
    m = mn;
    #pragma unroll
    for (int j = 0; j < 8; ++j) {
      acc[j]     = acc[j]     * co + w * (float)v0[j];
      acc[j + 8] = acc[j + 8] * co + w * (float)v1[j];
    }

    if (!more) break;
    k0 = nk0; k1 = nk1; v0 = nv0; v1 = nv1;
    off <<= 1;
  }

  const float inv = 1.0f / l;
  bf16x8 o0, o1;
  #pragma unroll
  for (int j = 0; j < 8; ++j) { o0[j] = (bf16_t)(acc[j] * inv); o1[j] = (bf16_t)(acc[j + 8] * inv); }
  *(bf16x8*)(O + base)     = o0;
  *(bf16x8*)(O + base + 8) = o1;
}

extern "C" void kernel_launch(void* const* d_in, const int* in_sizes, int n_in,
                              void* d_out, int out_size, void* d_ws, size_t ws_size,
                              hipStream_t stream) {
  (void)in_sizes; (void)n_in; (void)out_size; (void)ws_size;
  const float* x  = (const float*)d_in[0];
  const float* qw = (const float*)d_in[1];
  const float* kw = (const float*)d_in[2];
  const float* vw = (const float*)d_in[3];
  const float* ow = (const float*)d_in[4];
  // d_in[5] (positions) and d_in[6] (attend_mask) recomputed analytically in-kernel
  float* out = (float*)d_out;

  bf16_t* Xb  = (bf16_t*)d_ws;                       // 8192x1024
  bf16_t* Qb  = Xb  + (size_t)SEQ * DM;
  bf16_t* Kb  = Qb  + (size_t)SEQ * DM;
  bf16_t* Vb  = Kb  + (size_t)SEQ * DM;
  bf16_t* QWb = Vb  + (size_t)SEQ * DM;              // 1024x1024 x4
  bf16_t* KWb = QWb + (size_t)DM * DM;
  bf16_t* VWb = KWb + (size_t)DM * DM;
  bf16_t* OWb = VWb + (size_t)DM * DM;
  bf16_t* AO  = Qb;  // alias Q: each attn wave reads its own q row before writing it

  cvt_all<<<dim3(8192 + 4096), dim3(256), 0, stream>>>(x, qw, kw, vw, ow,
                                                       Xb, QWb, KWb, VWb, OWb);

  dim3 block(256);
  gemm_qkv<<<dim3(SEQ / 128, DM / 128, 3), block, 0, stream>>>(Xb, QWb, KWb, VWb, Qb, Kb, Vb);
  dilated_attn<<<dim3(SEQ / 4), block, 0, stream>>>(Qb, Kb, Vb, AO);
  gemm_out<<<dim3(SEQ / 128, DM / 64), block, 0, stream>>>(AO, OWb, out);
}

// Round 9
// 221.946 us; speedup vs baseline: 1.1162x; 1.0104x over previous
//
#include <hip/hip_runtime.h>
#include <hip/hip_bf16.h>

typedef __bf16 bf16_t;
typedef __bf16 bf16x4 __attribute__((ext_vector_type(4)));
typedef __bf16 bf16x8 __attribute__((ext_vector_type(8)));
typedef float floatx4 __attribute__((ext_vector_type(4)));

#define SEQ    8192
#define DM     1024
#define NHEADS 16
#define HDIM   64

// async global->LDS, 16B per lane; LDS dest is wave-uniform base + lane*16
__device__ __forceinline__ void async_ld16(bf16_t* lds, const bf16_t* g) {
  __builtin_amdgcn_global_load_lds(
      (__attribute__((address_space(1))) void*)g,
      (__attribute__((address_space(3))) void*)lds, 16, 0, 0);
}

// one launch converts x (8192 blocks) + 4 weight matrices (1024 blocks each)
__global__ __launch_bounds__(256)
void cvt_all(const float* __restrict__ x,  const float* __restrict__ qw,
             const float* __restrict__ kw, const float* __restrict__ vw,
             const float* __restrict__ ow,
             bf16_t* __restrict__ Xb,  bf16_t* __restrict__ QWb,
             bf16_t* __restrict__ KWb, bf16_t* __restrict__ VWb,
             bf16_t* __restrict__ OWb) {
  const int b = blockIdx.x;
  const float* in; bf16_t* out; int g;
  if (b < 8192) { in = x; out = Xb; g = b; }
  else {
    const int w  = (b - 8192) >> 10;
    const int wb = (b - 8192) & 1023;
    switch (w) {
      case 0:  in = qw; out = QWb; break;
      case 1:  in = kw; out = KWb; break;
      case 2:  in = vw; out = VWb; break;
      default: in = ow; out = OWb; break;
    }
    g = wb;
  }
  const int idx = (g * 256 + threadIdx.x) * 4;
  float4 v = *(const float4*)(in + idx);
  bf16x4 o = { (bf16_t)v.x, (bf16_t)v.y, (bf16_t)v.z, (bf16_t)v.w };
  *(bf16x4*)(out + idx) = o;
}

// XOR chunk swizzle (round 8, conflicts -> 0): LDS slot c of row r holds global
// k-chunk c ^ ((r>>1)&3); staging lane L fetches global chunk (L%4)^((L>>3)&3).

// ---------- QKV projection: 128x128 tile, BK=32, swizzled LDS (788 TF measured) ----------
__global__ __launch_bounds__(256)
void gemm_qkv(const bf16_t* __restrict__ A,
              const bf16_t* __restrict__ Bq, const bf16_t* __restrict__ Bk,
              const bf16_t* __restrict__ Bv,
              bf16_t* __restrict__ Cq, bf16_t* __restrict__ Ck, bf16_t* __restrict__ Cv)
{
  const bf16_t* B = (blockIdx.z == 0) ? Bq : (blockIdx.z == 1) ? Bk : Bv;
  bf16_t*       C = (blockIdx.z == 0) ? Cq : (blockIdx.z == 1) ? Ck : Cv;
  constexpr int Kdim = DM;
  __shared__ __attribute__((aligned(16))) bf16_t sA[128 * 32];
  __shared__ __attribute__((aligned(16))) bf16_t sB[128 * 32];

  const int tid  = threadIdx.x;
  const int wave = tid >> 6;
  const int lane = tid & 63;
  const int quad = lane >> 4;
  const int r16  = lane & 15;
  const int wr   = (wave >> 1) * 64;
  const int wc   = (wave & 1) * 64;

  const int gc = (lane & 3) ^ ((lane >> 3) & 3);
  const size_t arow0 = (size_t)blockIdx.x * 128 + wave * 32 + (lane >> 2);
  const size_t brow0 = (size_t)blockIdx.y * 128 + wave * 32 + (lane >> 2);
  const bf16_t* Ag = A + arow0 * Kdim + gc * 8;
  const bf16_t* Bg = B + brow0 * Kdim + gc * 8;
  bf16_t* sAw = sA + wave * 32 * 32;
  bf16_t* sBw = sB + wave * 32 * 32;

  const int slotA = ((quad ^ ((r16 >> 1) & 3)) * 8);

  floatx4 acc[4][4];
  #pragma unroll
  for (int i = 0; i < 4; ++i)
    #pragma unroll
    for (int j = 0; j < 4; ++j)
      acc[i][j] = (floatx4)(0.0f);

  for (int ko = 0; ko < Kdim; ko += 32) {
    async_ld16(sAw,           Ag + ko);
    async_ld16(sAw + 16 * 32, Ag + 16 * Kdim + ko);
    async_ld16(sBw,           Bg + ko);
    async_ld16(sBw + 16 * 32, Bg + 16 * Kdim + ko);
    __syncthreads();

    bf16x8 af[4], bfr[4];
    #pragma unroll
    for (int mi = 0; mi < 4; ++mi)
      af[mi] = *(const bf16x8*)&sA[(wr + mi * 16 + r16) * 32 + slotA];
    #pragma unroll
    for (int ni = 0; ni < 4; ++ni)
      bfr[ni] = *(const bf16x8*)&sB[(wc + ni * 16 + r16) * 32 + slotA];

    #pragma unroll
    for (int mi = 0; mi < 4; ++mi)
      #pragma unroll
      for (int ni = 0; ni < 4; ++ni)
        acc[mi][ni] = __builtin_amdgcn_mfma_f32_16x16x32_bf16(af[mi], bfr[ni], acc[mi][ni], 0, 0, 0);

    __syncthreads();
  }

  // C/D layout: col = lane&15, row = (lane>>4)*4 + reg  [measured m89/m91]
  const float scl = (blockIdx.z == 0) ? 0.125f : 1.0f;   // fold 1/sqrt(64) into Q
  const int crow0 = blockIdx.x * 128 + wr + quad * 4;
  const int ccol0 = blockIdx.y * 128 + wc + r16;
  #pragma unroll
  for (int mi = 0; mi < 4; ++mi)
    #pragma unroll
    for (int ni = 0; ni < 4; ++ni)
      #pragma unroll
      for (int r = 0; r < 4; ++r)
        C[(size_t)(crow0 + mi * 16 + r) * DM + (ccol0 + ni * 16)] = (bf16_t)(acc[mi][ni][r] * scl);
}

// ---------- Output projection: 128x128 tile (back from 128x64), swizzled LDS, f32 out ----------
__global__ __launch_bounds__(256)
void gemm_out(const bf16_t* __restrict__ A, const bf16_t* __restrict__ B,
              float* __restrict__ C)
{
  constexpr int Kdim = DM;
  __shared__ __attribute__((aligned(16))) bf16_t sA[128 * 32];
  __shared__ __attribute__((aligned(16))) bf16_t sB[128 * 32];

  const int tid  = threadIdx.x;
  const int wave = tid >> 6;
  const int lane = tid & 63;
  const int quad = lane >> 4;
  const int r16  = lane & 15;
  const int wr   = (wave >> 1) * 64;
  const int wc   = (wave & 1) * 64;

  const int gc = (lane & 3) ^ ((lane >> 3) & 3);
  const size_t arow0 = (size_t)blockIdx.x * 128 + wave * 32 + (lane >> 2);
  const size_t brow0 = (size_t)blockIdx.y * 128 + wave * 32 + (lane >> 2);
  const bf16_t* Ag = A + arow0 * Kdim + gc * 8;
  const bf16_t* Bg = B + brow0 * Kdim + gc * 8;
  bf16_t* sAw = sA + wave * 32 * 32;
  bf16_t* sBw = sB + wave * 32 * 32;

  const int slotA = ((quad ^ ((r16 >> 1) & 3)) * 8);

  floatx4 acc[4][4];
  #pragma unroll
  for (int i = 0; i < 4; ++i)
    #pragma unroll
    for (int j = 0; j < 4; ++j)
      acc[i][j] = (floatx4)(0.0f);

  for (int ko = 0; ko < Kdim; ko += 32) {
    async_ld16(sAw,           Ag + ko);
    async_ld16(sAw + 16 * 32, Ag + 16 * Kdim + ko);
    async_ld16(sBw,           Bg + ko);
    async_ld16(sBw + 16 * 32, Bg + 16 * Kdim + ko);
    __syncthreads();

    bf16x8 af[4], bfr[4];
    #pragma unroll
    for (int mi = 0; mi < 4; ++mi)
      af[mi] = *(const bf16x8*)&sA[(wr + mi * 16 + r16) * 32 + slotA];
    #pragma unroll
    for (int ni = 0; ni < 4; ++ni)
      bfr[ni] = *(const bf16x8*)&sB[(wc + ni * 16 + r16) * 32 + slotA];

    #pragma unroll
    for (int mi = 0; mi < 4; ++mi)
      #pragma unroll
      for (int ni = 0; ni < 4; ++ni)
        acc[mi][ni] = __builtin_amdgcn_mfma_f32_16x16x32_bf16(af[mi], bfr[ni], acc[mi][ni], 0, 0, 0);

    __syncthreads();
  }

  const int crow0 = blockIdx.x * 128 + wr + quad * 4;
  const int ccol0 = blockIdx.y * 128 + wc + r16;
  #pragma unroll
  for (int mi = 0; mi < 4; ++mi)
    #pragma unroll
    for (int ni = 0; ni < 4; ++ni)
      #pragma unroll
      for (int r = 0; r < 4; ++r)
        C[(size_t)(crow0 + mi * 16 + r) * DM + (ccol0 + ni * 16)] = acc[mi][ni][r];
}

// ---------- Attention: one wave per query, 16 heads; DEPTH-2 prefetch ring ----------
// Lane L owns dims [16L,16L+16) (head = L>>2). Attended set {i} U {i-2^t}.
// Each K/V load is issued 2 iterations before first use (~2 compute spans to
// cover L2 latency). Ring = 2 explicit slots (A/B), +32 VGPR vs depth-1 --
// no occupancy cliff (round 6's depth-14 hit VGPR 148 / occ 10% and regressed).
__global__ __launch_bounds__(256)
void dilated_attn(const bf16_t* __restrict__ Q, const bf16_t* __restrict__ K,
                  const bf16_t* __restrict__ V, bf16_t* O)
{
  const int lane = threadIdx.x & 63;
  const int qb   = (blockIdx.x & 7) * 256 + (blockIdx.x >> 3);  // XCD-affinity swizzle
  const int i    = qb * 4 + (threadIdx.x >> 6);
  const size_t base = (size_t)i * DM + lane * 16;

  bf16x8 q0 = *(const bf16x8*)(Q + base);
  bf16x8 q1 = *(const bf16x8*)(Q + base + 8);
  float qf[16];
  #pragma unroll
  for (int j = 0; j < 8; ++j) { qf[j] = (float)q0[j]; qf[j + 8] = (float)q1[j]; }

  // npos = 1 (i==0) else floor(log2 i) + 2   (wave-uniform)
  const int npos = (i == 0) ? 1 : (33 - __builtin_clz((unsigned)i));
  auto pos_addr = [&](int t) -> size_t {
    const int off = (t == 0) ? 0 : (1 << (t - 1));
    return (size_t)(i - off) * DM + lane * 16;
  };

  float m = -INFINITY, l = 0.0f;
  float acc[16];
  #pragma unroll
  for (int j = 0; j < 16; ++j) acc[j] = 0.0f;

  // slot A <- t=0, slot B <- t=1
  bf16x8 ka0, ka1, va0, va1, kb0 = {}, kb1 = {}, vb0 = {}, vb1 = {};
  {
    ka0 = *(const bf16x8*)(K + base); ka1 = *(const bf16x8*)(K + base + 8);
    va0 = *(const bf16x8*)(V + base); va1 = *(const bf16x8*)(V + base + 8);
  }
  if (npos > 1) {
    const size_t a = pos_addr(1);
    kb0 = *(const bf16x8*)(K + a); kb1 = *(const bf16x8*)(K + a + 8);
    vb0 = *(const bf16x8*)(V + a); vb1 = *(const bf16x8*)(V + a + 8);
  }

#define ATTN_STEP(K0, K1, V0, V1)                                              \
  {                                                                            \
    float sc = 0.0f;                                                           \
    _Pragma("unroll")                                                          \
    for (int j = 0; j < 8; ++j)                                                \
      sc += qf[j] * (float)K0[j] + qf[j + 8] * (float)K1[j];                   \
    sc += __shfl_xor(sc, 1, 64);                                               \
    sc += __shfl_xor(sc, 2, 64);                                               \
    float mn = fmaxf(m, sc);                                                   \
    float co = __expf(m - mn);                                                 \
    float w  = __expf(sc - mn);                                                \
    l = l * co + w;                                                            \
    m = mn;                                                                    \
    _Pragma("unroll")                                                          \
    for (int j = 0; j < 8; ++j) {                                              \
      acc[j]     = acc[j]     * co + w * (float)V0[j];                         \
      acc[j + 8] = acc[j + 8] * co + w * (float)V1[j];                         \
    }                                                                          \
  }

  int t = 0;
  while (true) {
    // consume slot A (loaded 2 iters ago), then refill it with t+2
    ATTN_STEP(ka0, ka1, va0, va1);
    if (t + 2 < npos) {
      const size_t a = pos_addr(t + 2);
      ka0 = *(const bf16x8*)(K + a); ka1 = *(const bf16x8*)(K + a + 8);
      va0 = *(const bf16x8*)(V + a); va1 = *(const bf16x8*)(V + a + 8);
    }
    if (++t >= npos) break;

    ATTN_STEP(kb0, kb1, vb0, vb1);
    if (t + 2 < npos) {
      const size_t a = pos_addr(t + 2);
      kb0 = *(const bf16x8*)(K + a); kb1 = *(const bf16x8*)(K + a + 8);
      vb0 = *(const bf16x8*)(V + a); vb1 = *(const bf16x8*)(V + a + 8);
    }
    if (++t >= npos) break;
  }
#undef ATTN_STEP

  const float inv = 1.0f / l;
  bf16x8 o0, o1;
  #pragma unroll
  for (int j = 0; j < 8; ++j) { o0[j] = (bf16_t)(acc[j] * inv); o1[j] = (bf16_t)(acc[j + 8] * inv); }
  *(bf16x8*)(O + base)     = o0;
  *(bf16x8*)(O + base + 8) = o1;
}

extern "C" void kernel_launch(void* const* d_in, const int* in_sizes, int n_in,
                              void* d_out, int out_size, void* d_ws, size_t ws_size,
                              hipStream_t stream) {
  (void)in_sizes; (void)n_in; (void)out_size; (void)ws_size;
  const float* x  = (const float*)d_in[0];
  const float* qw = (const float*)d_in[1];
  const float* kw = (const float*)d_in[2];
  const float* vw = (const float*)d_in[3];
  const float* ow = (const float*)d_in[4];
  // d_in[5] (positions) and d_in[6] (attend_mask) recomputed analytically in-kernel
  float* out = (float*)d_out;

  bf16_t* Xb  = (bf16_t*)d_ws;                       // 8192x1024
  bf16_t* Qb  = Xb  + (size_t)SEQ * DM;
  bf16_t* Kb  = Qb  + (size_t)SEQ * DM;
  bf16_t* Vb  = Kb  + (size_t)SEQ * DM;
  bf16_t* QWb = Vb  + (size_t)SEQ * DM;              // 1024x1024 x4
  bf16_t* KWb = QWb + (size_t)DM * DM;
  bf16_t* VWb = KWb + (size_t)DM * DM;
  bf16_t* OWb = VWb + (size_t)DM * DM;
  bf16_t* AO  = Qb;  // alias Q: each attn wave reads its own q row before writing it

  cvt_all<<<dim3(8192 + 4096), dim3(256), 0, stream>>>(x, qw, kw, vw, ow,
                                                       Xb, QWb, KWb, VWb, OWb);

  dim3 block(256);
  gemm_qkv<<<dim3(SEQ / 128, DM / 128, 3), block, 0, stream>>>(Xb, QWb, KWb, VWb, Qb, Kb, Vb);
  dilated_attn<<<dim3(SEQ / 4), block, 0, stream>>>(Qb, Kb, Vb, AO);
  gemm_out<<<dim3(SEQ / 128, DM / 128), block, 0, stream>>>(AO, OWb, out);
}

// Round 10
// 220.787 us; speedup vs baseline: 1.1221x; 1.0053x over previous
//
#include <hip/hip_runtime.h>
#include <hip/hip_bf16.h>

typedef __bf16 bf16_t;
typedef __bf16 bf16x4 __attribute__((ext_vector_type(4)));
typedef __bf16 bf16x8 __attribute__((ext_vector_type(8)));
typedef float floatx4 __attribute__((ext_vector_type(4)));

#define SEQ    8192
#define DM     1024
#define NHEADS 16
#define HDIM   64

// async global->LDS, 16B per lane; LDS dest is wave-uniform base + lane*16
__device__ __forceinline__ void async_ld16(bf16_t* lds, const bf16_t* g) {
  __builtin_amdgcn_global_load_lds(
      (__attribute__((address_space(1))) void*)g,
      (__attribute__((address_space(3))) void*)lds, 16, 0, 0);
}

// one launch converts x (8192 blocks) + 4 weight matrices (1024 blocks each)
__global__ __launch_bounds__(256)
void cvt_all(const float* __restrict__ x,  const float* __restrict__ qw,
             const float* __restrict__ kw, const float* __restrict__ vw,
             const float* __restrict__ ow,
             bf16_t* __restrict__ Xb,  bf16_t* __restrict__ QWb,
             bf16_t* __restrict__ KWb, bf16_t* __restrict__ VWb,
             bf16_t* __restrict__ OWb) {
  const int b = blockIdx.x;
  const float* in; bf16_t* out; int g;
  if (b < 8192) { in = x; out = Xb; g = b; }
  else {
    const int w  = (b - 8192) >> 10;
    const int wb = (b - 8192) & 1023;
    switch (w) {
      case 0:  in = qw; out = QWb; break;
      case 1:  in = kw; out = KWb; break;
      case 2:  in = vw; out = VWb; break;
      default: in = ow; out = OWb; break;
    }
    g = wb;
  }
  const int idx = (g * 256 + threadIdx.x) * 4;
  float4 v = *(const float4*)(in + idx);
  bf16x4 o = { (bf16_t)v.x, (bf16_t)v.y, (bf16_t)v.z, (bf16_t)v.w };
  *(bf16x4*)(out + idx) = o;
}

// XOR chunk swizzle (round 8, conflicts -> 0): LDS slot c of row r holds global
// k-chunk c ^ ((r>>1)&3); staging lane L fetches global chunk (L%4)^((L>>3)&3).

// ---------- QKV projection: 128x128 tile, BK=32, swizzled LDS (788 TF measured) ----------
__global__ __launch_bounds__(256)
void gemm_qkv(const bf16_t* __restrict__ A,
              const bf16_t* __restrict__ Bq, const bf16_t* __restrict__ Bk,
              const bf16_t* __restrict__ Bv,
              bf16_t* __restrict__ Cq, bf16_t* __restrict__ Ck, bf16_t* __restrict__ Cv)
{
  const bf16_t* B = (blockIdx.z == 0) ? Bq : (blockIdx.z == 1) ? Bk : Bv;
  bf16_t*       C = (blockIdx.z == 0) ? Cq : (blockIdx.z == 1) ? Ck : Cv;
  constexpr int Kdim = DM;
  __shared__ __attribute__((aligned(16))) bf16_t sA[128 * 32];
  __shared__ __attribute__((aligned(16))) bf16_t sB[128 * 32];

  const int tid  = threadIdx.x;
  const int wave = tid >> 6;
  const int lane = tid & 63;
  const int quad = lane >> 4;
  const int r16  = lane & 15;
  const int wr   = (wave >> 1) * 64;
  const int wc   = (wave & 1) * 64;

  const int gc = (lane & 3) ^ ((lane >> 3) & 3);
  const size_t arow0 = (size_t)blockIdx.x * 128 + wave * 32 + (lane >> 2);
  const size_t brow0 = (size_t)blockIdx.y * 128 + wave * 32 + (lane >> 2);
  const bf16_t* Ag = A + arow0 * Kdim + gc * 8;
  const bf16_t* Bg = B + brow0 * Kdim + gc * 8;
  bf16_t* sAw = sA + wave * 32 * 32;
  bf16_t* sBw = sB + wave * 32 * 32;

  const int slotA = ((quad ^ ((r16 >> 1) & 3)) * 8);

  floatx4 acc[4][4];
  #pragma unroll
  for (int i = 0; i < 4; ++i)
    #pragma unroll
    for (int j = 0; j < 4; ++j)
      acc[i][j] = (floatx4)(0.0f);

  for (int ko = 0; ko < Kdim; ko += 32) {
    async_ld16(sAw,           Ag + ko);
    async_ld16(sAw + 16 * 32, Ag + 16 * Kdim + ko);
    async_ld16(sBw,           Bg + ko);
    async_ld16(sBw + 16 * 32, Bg + 16 * Kdim + ko);
    __syncthreads();

    bf16x8 af[4], bfr[4];
    #pragma unroll
    for (int mi = 0; mi < 4; ++mi)
      af[mi] = *(const bf16x8*)&sA[(wr + mi * 16 + r16) * 32 + slotA];
    #pragma unroll
    for (int ni = 0; ni < 4; ++ni)
      bfr[ni] = *(const bf16x8*)&sB[(wc + ni * 16 + r16) * 32 + slotA];

    #pragma unroll
    for (int mi = 0; mi < 4; ++mi)
      #pragma unroll
      for (int ni = 0; ni < 4; ++ni)
        acc[mi][ni] = __builtin_amdgcn_mfma_f32_16x16x32_bf16(af[mi], bfr[ni], acc[mi][ni], 0, 0, 0);

    __syncthreads();
  }

  // C/D layout: col = lane&15, row = (lane>>4)*4 + reg  [measured m89/m91]
  const float scl = (blockIdx.z == 0) ? 0.125f : 1.0f;   // fold 1/sqrt(64) into Q
  const int crow0 = blockIdx.x * 128 + wr + quad * 4;
  const int ccol0 = blockIdx.y * 128 + wc + r16;
  #pragma unroll
  for (int mi = 0; mi < 4; ++mi)
    #pragma unroll
    for (int ni = 0; ni < 4; ++ni)
      #pragma unroll
      for (int r = 0; r < 4; ++r)
        C[(size_t)(crow0 + mi * 16 + r) * DM + (ccol0 + ni * 16)] = (bf16_t)(acc[mi][ni][r] * scl);
}

// ---------- Output projection: 128x128 tile, swizzled LDS, f32 out ----------
__global__ __launch_bounds__(256)
void gemm_out(const bf16_t* __restrict__ A, const bf16_t* __restrict__ B,
              float* __restrict__ C)
{
  constexpr int Kdim = DM;
  __shared__ __attribute__((aligned(16))) bf16_t sA[128 * 32];
  __shared__ __attribute__((aligned(16))) bf16_t sB[128 * 32];

  const int tid  = threadIdx.x;
  const int wave = tid >> 6;
  const int lane = tid & 63;
  const int quad = lane >> 4;
  const int r16  = lane & 15;
  const int wr   = (wave >> 1) * 64;
  const int wc   = (wave & 1) * 64;

  const int gc = (lane & 3) ^ ((lane >> 3) & 3);
  const size_t arow0 = (size_t)blockIdx.x * 128 + wave * 32 + (lane >> 2);
  const size_t brow0 = (size_t)blockIdx.y * 128 + wave * 32 + (lane >> 2);
  const bf16_t* Ag = A + arow0 * Kdim + gc * 8;
  const bf16_t* Bg = B + brow0 * Kdim + gc * 8;
  bf16_t* sAw = sA + wave * 32 * 32;
  bf16_t* sBw = sB + wave * 32 * 32;

  const int slotA = ((quad ^ ((r16 >> 1) & 3)) * 8);

  floatx4 acc[4][4];
  #pragma unroll
  for (int i = 0; i < 4; ++i)
    #pragma unroll
    for (int j = 0; j < 4; ++j)
      acc[i][j] = (floatx4)(0.0f);

  for (int ko = 0; ko < Kdim; ko += 32) {
    async_ld16(sAw,           Ag + ko);
    async_ld16(sAw + 16 * 32, Ag + 16 * Kdim + ko);
    async_ld16(sBw,           Bg + ko);
    async_ld16(sBw + 16 * 32, Bg + 16 * Kdim + ko);
    __syncthreads();

    bf16x8 af[4], bfr[4];
    #pragma unroll
    for (int mi = 0; mi < 4; ++mi)
      af[mi] = *(const bf16x8*)&sA[(wr + mi * 16 + r16) * 32 + slotA];
    #pragma unroll
    for (int ni = 0; ni < 4; ++ni)
      bfr[ni] = *(const bf16x8*)&sB[(wc + ni * 16 + r16) * 32 + slotA];

    #pragma unroll
    for (int mi = 0; mi < 4; ++mi)
      #pragma unroll
      for (int ni = 0; ni < 4; ++ni)
        acc[mi][ni] = __builtin_amdgcn_mfma_f32_16x16x32_bf16(af[mi], bfr[ni], acc[mi][ni], 0, 0, 0);

    __syncthreads();
  }

  const int crow0 = blockIdx.x * 128 + wr + quad * 4;
  const int ccol0 = blockIdx.y * 128 + wc + r16;
  #pragma unroll
  for (int mi = 0; mi < 4; ++mi)
    #pragma unroll
    for (int ni = 0; ni < 4; ++ni)
      #pragma unroll
      for (int r = 0; r < 4; ++r)
        C[(size_t)(crow0 + mi * 16 + r) * DM + (ccol0 + ni * 16)] = acc[mi][ni][r];
}

// ---------- Attention: SPLIT-WAVE (flash-decoding style) ----------
// 2 waves per query: wave sub handles positions t = sub, sub+2, ... (<=7 each),
// halving the serial softmax chain and doubling wave parallelism. Partial
// (m, l, acc[16]) states merge through LDS with one exp-rescale.
// Lane L owns dims [16L,16L+16) (head = L>>2); Q arrives pre-scaled.
// K/V traffic unchanged (each position read once); only Q row read twice.
__global__ __launch_bounds__(256)
void dilated_attn(const bf16_t* __restrict__ Q, const bf16_t* __restrict__ K,
                  const bf16_t* __restrict__ V, bf16_t* O)
{
  __shared__ float sM[2][64];
  __shared__ float sL[2][64];
  __shared__ float sAcc[2][64][17];   // stride 17: gcd(17,32)=1 -> conflict-free

  const int lane = threadIdx.x & 63;
  const int wv   = threadIdx.x >> 6;   // 0..3
  const int ql   = wv >> 1;            // query within block (0,1)
  const int sub  = wv & 1;             // position-parity subset
  const int qb   = (blockIdx.x & 7) * 512 + (blockIdx.x >> 3);  // XCD-affinity swizzle
  const int i    = qb * 2 + ql;
  const size_t base = (size_t)i * DM + lane * 16;

  bf16x8 q0 = *(const bf16x8*)(Q + base);
  bf16x8 q1 = *(const bf16x8*)(Q + base + 8);
  float qf[16];
  #pragma unroll
  for (int j = 0; j < 8; ++j) { qf[j] = (float)q0[j]; qf[j + 8] = (float)q1[j]; }

  // npos = 1 (i==0) else floor(log2 i) + 2   (wave-uniform)
  const int npos = (i == 0) ? 1 : (33 - __builtin_clz((unsigned)i));
  auto pos_addr = [&](int t) -> size_t {
    const int off = (t == 0) ? 0 : (1 << (t - 1));
    return (size_t)(i - off) * DM + lane * 16;
  };

  float m = -INFINITY, l = 0.0f;
  float acc[16];
  #pragma unroll
  for (int j = 0; j < 16; ++j) acc[j] = 0.0f;

  int t = sub;
  if (t < npos) {
    size_t a = pos_addr(t);
    bf16x8 k0 = *(const bf16x8*)(K + a), k1 = *(const bf16x8*)(K + a + 8);
    bf16x8 v0 = *(const bf16x8*)(V + a), v1 = *(const bf16x8*)(V + a + 8);
    while (true) {
      const int tn = t + 2;
      const bool more = (tn < npos);       // wave-uniform
      bf16x8 nk0, nk1, nv0, nv1;
      if (more) {                          // prefetch next position in subset
        const size_t na = pos_addr(tn);
        nk0 = *(const bf16x8*)(K + na); nk1 = *(const bf16x8*)(K + na + 8);
        nv0 = *(const bf16x8*)(V + na); nv1 = *(const bf16x8*)(V + na + 8);
      }

      float sc = 0.0f;
      #pragma unroll
      for (int j = 0; j < 8; ++j) sc += qf[j] * (float)k0[j] + qf[j + 8] * (float)k1[j];
      sc += __shfl_xor(sc, 1, 64);         // sum across the 4 lanes of this head
      sc += __shfl_xor(sc, 2, 64);

      float mn = fmaxf(m, sc);
      float co = __expf(m - mn);
      float w  = __expf(sc - mn);
      l = l * co + w;
      m = mn;
      #pragma unroll
      for (int j = 0; j < 8; ++j) {
        acc[j]     = acc[j]     * co + w * (float)v0[j];
        acc[j + 8] = acc[j + 8] * co + w * (float)v1[j];
      }

      if (!more) break;
      k0 = nk0; k1 = nk1; v0 = nv0; v1 = nv1;
      t = tn;
    }
  }

  // merge the two partial states per query
  if (sub == 1) {
    sM[ql][lane] = m;
    sL[ql][lane] = l;
    #pragma unroll
    for (int j = 0; j < 16; ++j) sAcc[ql][lane][j] = acc[j];
  }
  __syncthreads();
  if (sub == 0) {
    const float mb = sM[ql][lane], lb = sL[ql][lane];
    const float mt = fmaxf(m, mb);           // m finite (t=0 always valid for sub=0)
    const float ca = __expf(m - mt);
    const float cb = __expf(mb - mt);        // mb=-inf (i==0 case) -> cb=0, exact no-op
    const float inv = 1.0f / (l * ca + lb * cb);
    bf16x8 o0, o1;
    #pragma unroll
    for (int j = 0; j < 8; ++j) {
      o0[j] = (bf16_t)((acc[j]     * ca + sAcc[ql][lane][j]     * cb) * inv);
      o1[j] = (bf16_t)((acc[j + 8] * ca + sAcc[ql][lane][j + 8] * cb) * inv);
    }
    *(bf16x8*)(O + base)     = o0;
    *(bf16x8*)(O + base + 8) = o1;
  }
}

extern "C" void kernel_launch(void* const* d_in, const int* in_sizes, int n_in,
                              void* d_out, int out_size, void* d_ws, size_t ws_size,
                              hipStream_t stream) {
  (void)in_sizes; (void)n_in; (void)out_size; (void)ws_size;
  const float* x  = (const float*)d_in[0];
  const float* qw = (const float*)d_in[1];
  const float* kw = (const float*)d_in[2];
  const float* vw = (const float*)d_in[3];
  const float* ow = (const float*)d_in[4];
  // d_in[5] (positions) and d_in[6] (attend_mask) recomputed analytically in-kernel
  float* out = (float*)d_out;

  bf16_t* Xb  = (bf16_t*)d_ws;                       // 8192x1024
  bf16_t* Qb  = Xb  + (size_t)SEQ * DM;
  bf16_t* Kb  = Qb  + (size_t)SEQ * DM;
  bf16_t* Vb  = Kb  + (size_t)SEQ * DM;
  bf16_t* QWb = Vb  + (size_t)SEQ * DM;              // 1024x1024 x4
  bf16_t* KWb = QWb + (size_t)DM * DM;
  bf16_t* VWb = KWb + (size_t)DM * DM;
  bf16_t* OWb = VWb + (size_t)DM * DM;
  bf16_t* AO  = Qb;  // alias Q: each attn block reads its own q rows before writing them

  cvt_all<<<dim3(8192 + 4096), dim3(256), 0, stream>>>(x, qw, kw, vw, ow,
                                                       Xb, QWb, KWb, VWb, OWb);

  dim3 block(256);
  gemm_qkv<<<dim3(SEQ / 128, DM / 128, 3), block, 0, stream>>>(Xb, QWb, KWb, VWb, Qb, Kb, Vb);
  dilated_attn<<<dim3(SEQ / 2), block, 0, stream>>>(Qb, Kb, Vb, AO);
  gemm_out<<<dim3(SEQ / 128, DM / 128), block, 0, stream>>>(AO, OWb, out);
}

// Round 11
// 218.263 us; speedup vs baseline: 1.1351x; 1.0116x over previous
//
#include <hip/hip_runtime.h>
#include <hip/hip_bf16.h>

typedef __bf16 bf16_t;
typedef __bf16 bf16x4 __attribute__((ext_vector_type(4)));
typedef __bf16 bf16x8 __attribute__((ext_vector_type(8)));
typedef float floatx4 __attribute__((ext_vector_type(4)));

#define SEQ    8192
#define DM     1024
#define NHEADS 16
#define HDIM   64

// async global->LDS, 16B per lane; LDS dest is wave-uniform base + lane*16
__device__ __forceinline__ void async_ld16(bf16_t* lds, const bf16_t* g) {
  __builtin_amdgcn_global_load_lds(
      (__attribute__((address_space(1))) void*)g,
      (__attribute__((address_space(3))) void*)lds, 16, 0, 0);
}

// one launch converts x (8192 blocks) + 4 weight matrices (1024 blocks each)
__global__ __launch_bounds__(256)
void cvt_all(const float* __restrict__ x,  const float* __restrict__ qw,
             const float* __restrict__ kw, const float* __restrict__ vw,
             const float* __restrict__ ow,
             bf16_t* __restrict__ Xb,  bf16_t* __restrict__ QWb,
             bf16_t* __restrict__ KWb, bf16_t* __restrict__ VWb,
             bf16_t* __restrict__ OWb) {
  const int b = blockIdx.x;
  const float* in; bf16_t* out; int g;
  if (b < 8192) { in = x; out = Xb; g = b; }
  else {
    const int w  = (b - 8192) >> 10;
    const int wb = (b - 8192) & 1023;
    switch (w) {
      case 0:  in = qw; out = QWb; break;
      case 1:  in = kw; out = KWb; break;
      case 2:  in = vw; out = VWb; break;
      default: in = ow; out = OWb; break;
    }
    g = wb;
  }
  const int idx = (g * 256 + threadIdx.x) * 4;
  float4 v = *(const float4*)(in + idx);
  bf16x4 o = { (bf16_t)v.x, (bf16_t)v.y, (bf16_t)v.z, (bf16_t)v.w };
  *(bf16x4*)(out + idx) = o;
}

// XOR chunk swizzle (round 8, conflicts -> 0): LDS slot c of row r holds global
// k-chunk c ^ ((r>>1)&3); staging lane L fetches global chunk (L%4)^((L>>3)&3).

// ---------- QKV projection: 128x128 tile, BK=32, swizzled LDS (788 TF measured) ----------
__global__ __launch_bounds__(256)
void gemm_qkv(const bf16_t* __restrict__ A,
              const bf16_t* __restrict__ Bq, const bf16_t* __restrict__ Bk,
              const bf16_t* __restrict__ Bv,
              bf16_t* __restrict__ Cq, bf16_t* __restrict__ Ck, bf16_t* __restrict__ Cv)
{
  const bf16_t* B = (blockIdx.z == 0) ? Bq : (blockIdx.z == 1) ? Bk : Bv;
  bf16_t*       C = (blockIdx.z == 0) ? Cq : (blockIdx.z == 1) ? Ck : Cv;
  constexpr int Kdim = DM;
  __shared__ __attribute__((aligned(16))) bf16_t sA[128 * 32];
  __shared__ __attribute__((aligned(16))) bf16_t sB[128 * 32];

  const int tid  = threadIdx.x;
  const int wave = tid >> 6;
  const int lane = tid & 63;
  const int quad = lane >> 4;
  const int r16  = lane & 15;
  const int wr   = (wave >> 1) * 64;
  const int wc   = (wave & 1) * 64;

  const int gc = (lane & 3) ^ ((lane >> 3) & 3);
  const size_t arow0 = (size_t)blockIdx.x * 128 + wave * 32 + (lane >> 2);
  const size_t brow0 = (size_t)blockIdx.y * 128 + wave * 32 + (lane >> 2);
  const bf16_t* Ag = A + arow0 * Kdim + gc * 8;
  const bf16_t* Bg = B + brow0 * Kdim + gc * 8;
  bf16_t* sAw = sA + wave * 32 * 32;
  bf16_t* sBw = sB + wave * 32 * 32;

  const int slotA = ((quad ^ ((r16 >> 1) & 3)) * 8);

  floatx4 acc[4][4];
  #pragma unroll
  for (int i = 0; i < 4; ++i)
    #pragma unroll
    for (int j = 0; j < 4; ++j)
      acc[i][j] = (floatx4)(0.0f);

  for (int ko = 0; ko < Kdim; ko += 32) {
    async_ld16(sAw,           Ag + ko);
    async_ld16(sAw + 16 * 32, Ag + 16 * Kdim + ko);
    async_ld16(sBw,           Bg + ko);
    async_ld16(sBw + 16 * 32, Bg + 16 * Kdim + ko);
    __syncthreads();

    bf16x8 af[4], bfr[4];
    #pragma unroll
    for (int mi = 0; mi < 4; ++mi)
      af[mi] = *(const bf16x8*)&sA[(wr + mi * 16 + r16) * 32 + slotA];
    #pragma unroll
    for (int ni = 0; ni < 4; ++ni)
      bfr[ni] = *(const bf16x8*)&sB[(wc + ni * 16 + r16) * 32 + slotA];

    #pragma unroll
    for (int mi = 0; mi < 4; ++mi)
      #pragma unroll
      for (int ni = 0; ni < 4; ++ni)
        acc[mi][ni] = __builtin_amdgcn_mfma_f32_16x16x32_bf16(af[mi], bfr[ni], acc[mi][ni], 0, 0, 0);

    __syncthreads();
  }

  // C/D layout: col = lane&15, row = (lane>>4)*4 + reg  [measured m89/m91]
  const float scl = (blockIdx.z == 0) ? 0.125f : 1.0f;   // fold 1/sqrt(64) into Q
  const int crow0 = blockIdx.x * 128 + wr + quad * 4;
  const int ccol0 = blockIdx.y * 128 + wc + r16;
  #pragma unroll
  for (int mi = 0; mi < 4; ++mi)
    #pragma unroll
    for (int ni = 0; ni < 4; ++ni)
      #pragma unroll
      for (int r = 0; r < 4; ++r)
        C[(size_t)(crow0 + mi * 16 + r) * DM + (ccol0 + ni * 16)] = (bf16_t)(acc[mi][ni][r] * scl);
}

// ---------- Output projection: 128x64 tile -> 1024 blocks (4/CU), swizzled LDS, f32 out ----
// Round-2 data: this GEMM at 512 blocks (2/CU) ran ~2x worse per-FLOP than the
// 1536-block qkv launch; doubling resident blocks attacks that directly.
__global__ __launch_bounds__(256)
void gemm_out(const bf16_t* __restrict__ A, const bf16_t* __restrict__ B,
              float* __restrict__ C)
{
  constexpr int Kdim = DM;
  __shared__ __attribute__((aligned(16))) bf16_t sA[128 * 32];
  __shared__ __attribute__((aligned(16))) bf16_t sB[64 * 32];

  const int tid  = threadIdx.x;
  const int wave = tid >> 6;
  const int lane = tid & 63;
  const int quad = lane >> 4;
  const int r16  = lane & 15;
  const int wr   = (wave >> 1) * 64;   // wave row offset in 128-row tile
  const int wc   = (wave & 1) * 32;    // wave col offset in 64-col tile

  const int gc = (lane & 3) ^ ((lane >> 3) & 3);
  const size_t arow = (size_t)blockIdx.x * 128 + wave * 32 + (lane >> 2);
  const size_t brow = (size_t)blockIdx.y * 64 + wave * 16 + (lane >> 2);
  const bf16_t* Ag = A + arow * Kdim + gc * 8;
  const bf16_t* Bg = B + brow * Kdim + gc * 8;
  bf16_t* sAw = sA + wave * 32 * 32;
  bf16_t* sBw = sB + wave * 16 * 32;

  const int slotA = ((quad ^ ((r16 >> 1) & 3)) * 8);

  floatx4 acc[4][2];
  #pragma unroll
  for (int i = 0; i < 4; ++i)
    #pragma unroll
    for (int j = 0; j < 2; ++j)
      acc[i][j] = (floatx4)(0.0f);

  for (int ko = 0; ko < Kdim; ko += 32) {
    async_ld16(sAw,           Ag + ko);
    async_ld16(sAw + 16 * 32, Ag + 16 * Kdim + ko);
    async_ld16(sBw,           Bg + ko);
    __syncthreads();

    bf16x8 af[4], bfr[2];
    #pragma unroll
    for (int mi = 0; mi < 4; ++mi)
      af[mi] = *(const bf16x8*)&sA[(wr + mi * 16 + r16) * 32 + slotA];
    #pragma unroll
    for (int ni = 0; ni < 2; ++ni)
      bfr[ni] = *(const bf16x8*)&sB[(wc + ni * 16 + r16) * 32 + slotA];

    #pragma unroll
    for (int mi = 0; mi < 4; ++mi)
      #pragma unroll
      for (int ni = 0; ni < 2; ++ni)
        acc[mi][ni] = __builtin_amdgcn_mfma_f32_16x16x32_bf16(af[mi], bfr[ni], acc[mi][ni], 0, 0, 0);

    __syncthreads();
  }

  const int crow0 = blockIdx.x * 128 + wr + quad * 4;
  const int ccol0 = blockIdx.y * 64 + wc + r16;
  #pragma unroll
  for (int mi = 0; mi < 4; ++mi)
    #pragma unroll
    for (int ni = 0; ni < 2; ++ni)
      #pragma unroll
      for (int r = 0; r < 4; ++r)
        C[(size_t)(crow0 + mi * 16 + r) * DM + (ccol0 + ni * 16)] = acc[mi][ni][r];
}

// ---------- Attention: SPLIT-WAVE (round 10, kept) ----------
// 2 waves per query: wave sub handles positions t = sub, sub+2, ...; partial
// (m, l, acc[16]) states merge through LDS with one exp-rescale.
// Lane L owns dims [16L,16L+16) (head = L>>2); Q arrives pre-scaled.
__global__ __launch_bounds__(256)
void dilated_attn(const bf16_t* __restrict__ Q, const bf16_t* __restrict__ K,
                  const bf16_t* __restrict__ V, bf16_t* O)
{
  __shared__ float sM[2][64];
  __shared__ float sL[2][64];
  __shared__ float sAcc[2][64][17];   // stride 17: gcd(17,32)=1 -> conflict-free

  const int lane = threadIdx.x & 63;
  const int wv   = threadIdx.x >> 6;   // 0..3
  const int ql   = wv >> 1;            // query within block (0,1)
  const int sub  = wv & 1;             // position-parity subset
  const int qb   = (blockIdx.x & 7) * 512 + (blockIdx.x >> 3);  // XCD-affinity swizzle
  const int i    = qb * 2 + ql;
  const size_t base = (size_t)i * DM + lane * 16;

  bf16x8 q0 = *(const bf16x8*)(Q + base);
  bf16x8 q1 = *(const bf16x8*)(Q + base + 8);
  float qf[16];
  #pragma unroll
  for (int j = 0; j < 8; ++j) { qf[j] = (float)q0[j]; qf[j + 8] = (float)q1[j]; }

  // npos = 1 (i==0) else floor(log2 i) + 2   (wave-uniform)
  const int npos = (i == 0) ? 1 : (33 - __builtin_clz((unsigned)i));
  auto pos_addr = [&](int t) -> size_t {
    const int off = (t == 0) ? 0 : (1 << (t - 1));
    return (size_t)(i - off) * DM + lane * 16;
  };

  float m = -INFINITY, l = 0.0f;
  float acc[16];
  #pragma unroll
  for (int j = 0; j < 16; ++j) acc[j] = 0.0f;

  int t = sub;
  if (t < npos) {
    size_t a = pos_addr(t);
    bf16x8 k0 = *(const bf16x8*)(K + a), k1 = *(const bf16x8*)(K + a + 8);
    bf16x8 v0 = *(const bf16x8*)(V + a), v1 = *(const bf16x8*)(V + a + 8);
    while (true) {
      const int tn = t + 2;
      const bool more = (tn < npos);       // wave-uniform
      bf16x8 nk0, nk1, nv0, nv1;
      if (more) {                          // prefetch next position in subset
        const size_t na = pos_addr(tn);
        nk0 = *(const bf16x8*)(K + na); nk1 = *(const bf16x8*)(K + na + 8);
        nv0 = *(const bf16x8*)(V + na); nv1 = *(const bf16x8*)(V + na + 8);
      }

      float sc = 0.0f;
      #pragma unroll
      for (int j = 0; j < 8; ++j) sc += qf[j] * (float)k0[j] + qf[j + 8] * (float)k1[j];
      sc += __shfl_xor(sc, 1, 64);         // sum across the 4 lanes of this head
      sc += __shfl_xor(sc, 2, 64);

      float mn = fmaxf(m, sc);
      float co = __expf(m - mn);
      float w  = __expf(sc - mn);
      l = l * co + w;
      m = mn;
      #pragma unroll
      for (int j = 0; j < 8; ++j) {
        acc[j]     = acc[j]     * co + w * (float)v0[j];
        acc[j + 8] = acc[j + 8] * co + w * (float)v1[j];
      }

      if (!more) break;
      k0 = nk0; k1 = nk1; v0 = nv0; v1 = nv1;
      t = tn;
    }
  }

  // merge the two partial states per query
  if (sub == 1) {
    sM[ql][lane] = m;
    sL[ql][lane] = l;
    #pragma unroll
    for (int j = 0; j < 16; ++j) sAcc[ql][lane][j] = acc[j];
  }
  __syncthreads();
  if (sub == 0) {
    const float mb = sM[ql][lane], lb = sL[ql][lane];
    const float mt = fmaxf(m, mb);           // m finite (t=0 always valid for sub=0)
    const float ca = __expf(m - mt);
    const float cb = __expf(mb - mt);        // mb=-inf (i==0 case) -> cb=0, exact no-op
    const float inv = 1.0f / (l * ca + lb * cb);
    bf16x8 o0, o1;
    #pragma unroll
    for (int j = 0; j < 8; ++j) {
      o0[j] = (bf16_t)((acc[j]     * ca + sAcc[ql][lane][j]     * cb) * inv);
      o1[j] = (bf16_t)((acc[j + 8] * ca + sAcc[ql][lane][j + 8] * cb) * inv);
    }
    *(bf16x8*)(O + base)     = o0;
    *(bf16x8*)(O + base + 8) = o1;
  }
}

extern "C" void kernel_launch(void* const* d_in, const int* in_sizes, int n_in,
                              void* d_out, int out_size, void* d_ws, size_t ws_size,
                              hipStream_t stream) {
  (void)in_sizes; (void)n_in; (void)out_size; (void)ws_size;
  const float* x  = (const float*)d_in[0];
  const float* qw = (const float*)d_in[1];
  const float* kw = (const float*)d_in[2];
  const float* vw = (const float*)d_in[3];
  const float* ow = (const float*)d_in[4];
  // d_in[5] (positions) and d_in[6] (attend_mask) recomputed analytically in-kernel
  float* out = (float*)d_out;

  bf16_t* Xb  = (bf16_t*)d_ws;                       // 8192x1024
  bf16_t* Qb  = Xb  + (size_t)SEQ * DM;
  bf16_t* Kb  = Qb  + (size_t)SEQ * DM;
  bf16_t* Vb  = Kb  + (size_t)SEQ * DM;
  bf16_t* QWb = Vb  + (size_t)SEQ * DM;              // 1024x1024 x4
  bf16_t* KWb = QWb + (size_t)DM * DM;
  bf16_t* VWb = KWb + (size_t)DM * DM;
  bf16_t* OWb = VWb + (size_t)DM * DM;
  bf16_t* AO  = Qb;  // alias Q: each attn block reads its own q rows before writing them

  cvt_all<<<dim3(8192 + 4096), dim3(256), 0, stream>>>(x, qw, kw, vw, ow,
                                                       Xb, QWb, KWb, VWb, OWb);

  dim3 block(256);
  gemm_qkv<<<dim3(SEQ / 128, DM / 128, 3), block, 0, stream>>>(Xb, QWb, KWb, VWb, Qb, Kb, Vb);
  dilated_attn<<<dim3(SEQ / 2), block, 0, stream>>>(Qb, Kb, Vb, AO);
  gemm_out<<<dim3(SEQ / 128, DM / 64), block, 0, stream>>>(AO, OWb, out);
}